// Round 1
// baseline (451.456 us; speedup 1.0000x reference)
//
#include <hip/hip_runtime.h>

#define NUM_HEADS 16
#define HEAD_DIM 128
#define KV_BLOCK 16          // tokens per physical KV block
#define BATCH 16
#define BLOCKS_PER_SEQ 128
#define MAX_CTX 2048
#define PART_TOKENS 256      // tokens per partition (16 KV blocks)
#define NUM_PARTS (MAX_CTX / PART_TOKENS)   // 8
#define WS_STRIDE (HEAD_DIM + 2)            // per-partition: 128 floats O, m, l
#define NEG_BIG -1e30f

// Kernel 1: one block per (batch, head, partition). 256 threads.
// Phase 1: scores via half-wave (32 lanes x float4) per token.
// Phase 2: partition softmax in LDS.
// Phase 3: P*V accumulation, 8 tokens in flight (one per half-wave).
__global__ __launch_bounds__(256) void paged_attn_partial(
    const float* __restrict__ q,          // [B, H, D]
    const float* __restrict__ kcache,     // [NB, KV_BLOCK, H, D]
    const float* __restrict__ vcache,     // [NB, KV_BLOCK, H, D]
    const int*   __restrict__ block_tables, // [B, BLOCKS_PER_SEQ]
    const int*   __restrict__ ctx_lens,   // [B]
    float* __restrict__ ws)               // [B*H*NUM_PARTS, WS_STRIDE]
{
    const int part = blockIdx.x;   // 0..NUM_PARTS-1
    const int h    = blockIdx.y;   // 0..H-1
    const int b    = blockIdx.z;   // 0..B-1
    const int tid  = threadIdx.x;  // 0..255

    float* wsp = ws + ((size_t)((b * NUM_HEADS + h) * NUM_PARTS + part)) * WS_STRIDE;

    const int ctx = ctx_lens[b];
    const int t0  = part * PART_TOKENS;
    int valid_n = ctx - t0;
    if (valid_n > PART_TOKENS) valid_n = PART_TOKENS;

    if (valid_n <= 0) {
        // empty partition: write a neutral partial
        if (tid < HEAD_DIM) wsp[tid] = 0.0f;
        if (tid == 0) { wsp[HEAD_DIM] = NEG_BIG; wsp[HEAD_DIM + 1] = 0.0f; }
        return;
    }

    __shared__ __align__(16) float sQ[HEAD_DIM];
    __shared__ float sScores[PART_TOKENS];
    __shared__ int   sBlocks[PART_TOKENS / KV_BLOCK];   // 16 physical block ids
    __shared__ __align__(16) float sAcc[8][HEAD_DIM];   // phase-3 cross-group reduce
    __shared__ float sRedMax[4], sRedSum[4];

    if (tid < HEAD_DIM) sQ[tid] = q[((size_t)b * NUM_HEADS + h) * HEAD_DIM + tid];
    if (tid < PART_TOKENS / KV_BLOCK)
        sBlocks[tid] = block_tables[b * BLOCKS_PER_SEQ + part * (PART_TOKENS / KV_BLOCK) + tid];
    __syncthreads();

    const int hw     = tid >> 5;   // half-wave id 0..7
    const int lane32 = tid & 31;
    const float scale = 0.088388347648318447f;  // 1/sqrt(128)

    // ---- Phase 1: scores ----
    const float4 q4 = *(const float4*)(&sQ[lane32 * 4]);
    for (int t = hw; t < PART_TOKENS; t += 8) {
        float s;
        if (t < valid_n) {
            const int phys = sBlocks[t >> 4];
            const float* kptr = kcache +
                ((((size_t)phys * KV_BLOCK + (t & 15)) * NUM_HEADS + h) * HEAD_DIM);
            const float4 k4 = *(const float4*)(kptr + lane32 * 4);
            float d = k4.x * q4.x + k4.y * q4.y + k4.z * q4.z + k4.w * q4.w;
            #pragma unroll
            for (int off = 1; off < 32; off <<= 1)
                d += __shfl_xor(d, off, 64);   // xor<32 stays inside the 32-lane half
            s = d * scale;
        } else {
            s = NEG_BIG;
        }
        if (lane32 == 0) sScores[t] = s;
    }
    __syncthreads();

    // ---- Phase 2: partition softmax ----
    float v = sScores[tid];
    float r = v;
    #pragma unroll
    for (int off = 32; off > 0; off >>= 1) r = fmaxf(r, __shfl_xor(r, off, 64));
    const int wid = tid >> 6;
    if ((tid & 63) == 0) sRedMax[wid] = r;
    __syncthreads();
    const float m = fmaxf(fmaxf(sRedMax[0], sRedMax[1]), fmaxf(sRedMax[2], sRedMax[3]));

    const float p = __expf(v - m);   // invalid scores underflow to 0
    sScores[tid] = p;
    float s = p;
    #pragma unroll
    for (int off = 32; off > 0; off >>= 1) s += __shfl_xor(s, off, 64);
    if ((tid & 63) == 0) sRedSum[wid] = s;
    __syncthreads();
    const float l = sRedSum[0] + sRedSum[1] + sRedSum[2] + sRedSum[3];

    // ---- Phase 3: O_partial = sum_t p[t] * V[t, :] ----
    float4 acc = make_float4(0.f, 0.f, 0.f, 0.f);
    for (int t = hw; t < valid_n; t += 8) {
        const float pt = sScores[t];
        const int phys = sBlocks[t >> 4];
        const float* vptr = vcache +
            ((((size_t)phys * KV_BLOCK + (t & 15)) * NUM_HEADS + h) * HEAD_DIM);
        const float4 v4 = *(const float4*)(vptr + lane32 * 4);
        acc.x += pt * v4.x; acc.y += pt * v4.y; acc.z += pt * v4.z; acc.w += pt * v4.w;
    }
    *(float4*)(&sAcc[hw][lane32 * 4]) = acc;
    __syncthreads();

    if (tid < HEAD_DIM) {
        float o = 0.f;
        #pragma unroll
        for (int g = 0; g < 8; ++g) o += sAcc[g][tid];
        wsp[tid] = o;                         // unnormalized (post exp(.-m))
    }
    if (tid == 0) { wsp[HEAD_DIM] = m; wsp[HEAD_DIM + 1] = l; }
}

// Kernel 2: combine NUM_PARTS partials per (b,h) with log-sum-exp merge.
__global__ __launch_bounds__(128) void paged_attn_reduce(
    const float* __restrict__ ws,
    float* __restrict__ out)   // [B, H, D]
{
    const int bh  = blockIdx.x;          // 0..B*H-1
    const int tid = threadIdx.x;         // 0..127
    const float* base = ws + (size_t)bh * NUM_PARTS * WS_STRIDE;

    __shared__ float sM[NUM_PARTS], sL[NUM_PARTS];
    if (tid < NUM_PARTS) {
        sM[tid] = base[tid * WS_STRIDE + HEAD_DIM];
        sL[tid] = base[tid * WS_STRIDE + HEAD_DIM + 1];
    }
    __syncthreads();

    float M = NEG_BIG;
    #pragma unroll
    for (int p = 0; p < NUM_PARTS; ++p) M = fmaxf(M, sM[p]);

    float w[NUM_PARTS];
    float L = 0.f;
    #pragma unroll
    for (int p = 0; p < NUM_PARTS; ++p) {
        const float wi = (sL[p] > 0.f) ? __expf(sM[p] - M) : 0.f;
        w[p] = wi;
        L += wi * sL[p];
    }

    float o = 0.f;
    #pragma unroll
    for (int p = 0; p < NUM_PARTS; ++p)
        o += w[p] * base[p * WS_STRIDE + tid];

    out[(size_t)bh * HEAD_DIM + tid] = o / L;
}

extern "C" void kernel_launch(void* const* d_in, const int* in_sizes, int n_in,
                              void* d_out, int out_size, void* d_ws, size_t ws_size,
                              hipStream_t stream) {
    const float* q  = (const float*)d_in[0];
    const float* k  = (const float*)d_in[1];
    const float* v  = (const float*)d_in[2];
    const int*   bt = (const int*)d_in[3];
    const int*   cl = (const int*)d_in[4];
    // d_in[5] = max_context_len (compile-time constant 2048, unused)
    float* out = (float*)d_out;
    float* ws  = (float*)d_ws;   // needs 256*8*130*4 = ~1.02 MB

    dim3 grid1(NUM_PARTS, NUM_HEADS, BATCH);
    paged_attn_partial<<<grid1, 256, 0, stream>>>(q, k, v, bt, cl, ws);

    dim3 grid2(BATCH * NUM_HEADS);
    paged_attn_reduce<<<grid2, 128, 0, stream>>>(ws, out);
}